// Round 9
// baseline (338.367 us; speedup 1.0000x reference)
//
#include <hip/hip_runtime.h>
#include <math.h>

#define NNODES 100000
#define NEDGES 1600000
#define NPOS   4096      // 32 seqs * 128 steps
#define NSEQ   32
#define TSTEPS 128

typedef float f32x4 __attribute__((ext_vector_type(4)));
typedef unsigned u32x4 __attribute__((ext_vector_type(4)));
typedef _Float16 h2v __attribute__((ext_vector_type(2)));

// ---- ws layout (bytes) ----
#define OFF_SLOT   0          // int[100000]  (dead after k_pregemm)
#define OFF_AGG    400128     // float[4096*128] (dead after k_pregemm; overlaid by wh16)
#define OFF_CNT    2497280    // float[4096]
#define OFF_WF     2513664    // float[1024*128]
#define OFF_BIASF  3037952    // float[1024]
#define OFF_PREG   3042048    // float[128][32s][8m][4q][32d]
#define OFF_HS     19819264   // float[129][32][256]
// fp16 weight images overlay the dead agg region (valid only after k_pregemm):
//   wh16A: u32[192][512]   (gates 0..2, register-resident)   384 KiB
//   wh16L: u32x4[16][512]  (gate 3, LDS-resident)            128 KiB
#define OFF_WH16A  OFF_AGG
#define OFF_WH16L  (OFF_AGG + 192 * 512 * 4)

// fp16 dot2 with f32 accumulate: D = w.h[0]*h.h[0] + w.h[1]*h.h[1] + acc.
// Products are exact in f32 (11-bit mantissas); only input quantization matters.
static __device__ __forceinline__ float fdot2(unsigned w, unsigned h, float acc) {
#if __has_builtin(__builtin_amdgcn_fdot2)
  h2v wv, hv;
  __builtin_memcpy(&wv, &w, 4);
  __builtin_memcpy(&hv, &h, 4);
  return __builtin_amdgcn_fdot2(wv, hv, acc, false);
#else
  asm("v_dot2_f32_f16 %0, %1, %2, %0" : "+v"(acc) : "v"(w), "v"(h));
  return acc;
#endif
}

// ---------------- init ----------------
__global__ void k_init(int* slotmap, float* agg, float* cnt, float* hs0) {
  int i = blockIdx.x * blockDim.x + threadIdx.x;
  int stride = gridDim.x * blockDim.x;
  for (int idx = i; idx < 4096 * 128; idx += stride) agg[idx] = 0.f;
  for (int idx = i; idx < NNODES; idx += stride) slotmap[idx] = -1;
  for (int idx = i; idx < 4096; idx += stride) cnt[idx] = 0.f;
  for (int idx = i; idx < 8192; idx += stride) hs0[idx] = 0.f;
}

// ---------------- mark needed nodes ----------------
__global__ void k_mark(const int* __restrict__ input_ids, int* __restrict__ slotmap) {
  int p = blockIdx.x * blockDim.x + threadIdx.x;
  if (p < NPOS) atomicCAS(&slotmap[input_ids[p]], -1, p);
}

// ---------------- edge pass: masked segment-sum ----------------
__global__ void k_edge(const int* __restrict__ src, const int* __restrict__ dst,
                       const float* __restrict__ ev, const float* __restrict__ emb,
                       const int* __restrict__ slotmap,
                       float* __restrict__ agg, float* __restrict__ cnt) {
  int e = blockIdx.x * 256 + threadIdx.x;
  int lane = threadIdx.x & 63;
  int d = dst[e];
  int slot = slotmap[d];
  int sn = 0; float vv = 0.f;
  if (slot >= 0) { sn = src[e]; vv = ev[e]; }
  unsigned long long m = __ballot(slot >= 0);
  while (m) {
    int j = __ffsll(m) - 1;
    m &= m - 1;
    int sl = __shfl(slot, j);
    int s2 = __shfl(sn, j);
    float v = __shfl(vv, j);
    float2 em = *(const float2*)&emb[(size_t)s2 * 128 + 2 * lane];
    atomicAdd(&agg[sl * 128 + 2 * lane],     em.x * v);
    atomicAdd(&agg[sl * 128 + 2 * lane + 1], em.y * v);
    if (lane == 0) atomicAdd(&cnt[sl], 1.f);
  }
}

// ---------------- divide by count ----------------
__global__ void k_div(float* __restrict__ agg, const float* __restrict__ cnt) {
  int i = blockIdx.x * blockDim.x + threadIdx.x;
  agg[i] /= fmaxf(cnt[i >> 7], 1.f);
}

// ---------------- fuse W_f = w_ih @ W1, bias_f ----------------
__global__ void k_fuse(const float* __restrict__ w_ih, const float* __restrict__ W1,
                       const float* __restrict__ b1, const float* __restrict__ b_ih,
                       const float* __restrict__ b_hh,
                       float* __restrict__ Wf, float* __restrict__ bf) {
  int row = blockIdx.x;
  int e = threadIdx.x;
  float acc = 0.f;
  for (int m2 = 0; m2 < 256; ++m2) acc += w_ih[row * 256 + m2] * W1[m2 * 128 + e];
  Wf[row * 128 + e] = acc;
  if (e == 0) {
    float bacc = b_ih[row] + b_hh[row];
    for (int m2 = 0; m2 < 256; ++m2) bacc += w_ih[row * 256 + m2] * b1[m2];
    bf[row] = bacc;
  }
}

// ---------------- pre-gates GEMM: preg[t][s][m][q][32d] ----------------
__global__ __launch_bounds__(256, 2) void k_pregemm(
    const float* __restrict__ hnode, const float* __restrict__ Wf,
    const float* __restrict__ bf, const int* __restrict__ slotmap,
    const int* __restrict__ input_ids, float* __restrict__ preg) {
  __shared__ float Ash[64][132];
  __shared__ float Bsh[64][132];
  __shared__ int slots[64];
  int tid = threadIdx.x;
  int bm = (blockIdx.x & 63) * 64;
  int bn = (blockIdx.x >> 6) * 64;
  if (tid < 64) slots[tid] = slotmap[input_ids[bm + tid]];
  __syncthreads();
#pragma unroll
  for (int i = 0; i < 8; ++i) {
    int idx = tid + 256 * i;
    int r = idx >> 5, c = idx & 31;
    *(float4*)&Ash[r][c * 4] = *(const float4*)&hnode[slots[r] * 128 + c * 4];
    *(float4*)&Bsh[r][c * 4] = *(const float4*)&Wf[(bn + r) * 128 + c * 4];
  }
  __syncthreads();
  int tx = tid & 15, ty = tid >> 4;
  float acc[4][4] = {};
  for (int k = 0; k < 128; k += 4) {
    float4 a[4], bb[4];
#pragma unroll
    for (int i = 0; i < 4; ++i) a[i] = *(const float4*)&Ash[tx + 16 * i][k];
#pragma unroll
    for (int j = 0; j < 4; ++j) bb[j] = *(const float4*)&Bsh[ty + 16 * j][k];
#pragma unroll
    for (int i = 0; i < 4; ++i)
#pragma unroll
      for (int j = 0; j < 4; ++j)
        acc[i][j] += a[i].x * bb[j].x + a[i].y * bb[j].y + a[i].z * bb[j].z + a[i].w * bb[j].w;
  }
#pragma unroll
  for (int j = 0; j < 4; ++j) {
    int row = bn + ty + 16 * j;
    float bias = bf[row];
    int q  = row >> 8;
    int mm = (row >> 5) & 7;
    int dl = row & 31;
#pragma unroll
    for (int i = 0; i < 4; ++i) {
      int p = bm + tx + 16 * i;
      int s = p >> 7, tt = p & 127;
      preg[(((size_t)(tt * 32 + s) * 8 + mm) * 4 + q) * 32 + dl] = acc[i][j] + bias;
    }
  }
}

// ---------------- w_hh f32 -> packed fp16 images (RNE) ----------------
// Layouts are tailored to k_lstm's thread mapping (tid = kseg*256 + d):
//   gates q=0..2: wh16A[(q*64 + jj)*512 + tid]  (coalesced prologue loads)
//   gate  q=3:    wh16L[((jj>>2)*512 + tid)*4 + (jj&3)]  (b128 LDS slots)
// where pair jj = local pair index 0..63 within the thread's 128-k slice.
__global__ void k_wcvt(const float* __restrict__ w_hh,
                       unsigned* __restrict__ wA, unsigned* __restrict__ wL) {
  int idx = blockIdx.x * 256 + threadIdx.x;   // 0..131071
  int row = idx >> 7;          // 0..1023 : q*256 + d
  int j   = idx & 127;         // global pair index (k = 2j, 2j+1)
  float x0 = w_hh[(size_t)row * 256 + 2 * j];
  float x1 = w_hh[(size_t)row * 256 + 2 * j + 1];
  union { _Float16 f[2]; unsigned u; } pk;
  pk.f[0] = (_Float16)x0;
  pk.f[1] = (_Float16)x1;
  int q = row >> 8, d = row & 255;
  int kseg = j >> 6, jj = j & 63;
  int tid = kseg * 256 + d;
  if (q < 3) {
    wA[(q * 64 + jj) * 512 + tid] = pk.u;
  } else {
    wL[((jj >> 2) * 512 + tid) * 4 + (jj & 3)] = pk.u;
  }
}

// ---------------- LSTM: ONE sequence per CU, fp16 weights, zero communication ----
// R6-R8 post-mortem: wv[192] never became register-resident (VGPR_Count=128 =
// the 4-waves/EU default budget); the compiler re-streams the weights every
// step (active-CU VALUBusy ~64%, ~1500 extra cyc/step of remat/spill traffic).
// HIP __launch_bounds__ arg2 (both 2 and 1) never changed the backend budget.
// Fix A: drive the backend DIRECTLY -- amdgpu_flat_work_group_size(512,512) +
// amdgpu_waves_per_eu(2): LLVM derives the VGPR ceiling from the waves-per-EU
// MINIMUM => 512-slot RF / 2 = 256 VGPRs/wave (physically true anyway: 132KB
// LDS forces 1 block/CU = 2 waves/SIMD). Fix B: asm-pin each loaded weight
// word ("+v") so the compiler cannot rematerialize the loads into the loop --
// with a 256 budget it must keep all 192 live in VGPRs (192 + ~40 ~= 232).
// Per step: 256 dot2/thread (1024 cyc/SIMD) + LDS gate-o/h stream (~2000 cyc
// DS, overlapped) + 2 barriers => ~0.7-0.9us/step target.
__global__ __attribute__((amdgpu_flat_work_group_size(512, 512),
                          amdgpu_waves_per_eu(2)))
void k_lstm(
    const unsigned* __restrict__ wh16A, const unsigned* __restrict__ wh16L,
    const float* __restrict__ preg, float* __restrict__ hs) {
  __shared__ __align__(16) unsigned whL[16 * 512 * 4];  // 128 KiB: gate-o weights
  __shared__ __align__(16) unsigned h16[128];           // 256 fp16 h, packed pairs
  __shared__ __align__(16) float    accb[256 * 4];      // kseg1 partials
  const int tid  = threadIdx.x;
  const int s    = blockIdx.x;
  const int kseg = tid >> 8;
  const int d    = tid & 255;
  const bool owner = (kseg == 0);

  // ---- prologue: weights into VGPRs (gates 0..2) and LDS (gate 3) ----
  unsigned wv[192];
  {
    const unsigned* wa = wh16A + tid;
#pragma unroll
    for (int e = 0; e < 192; ++e) wv[e] = wa[e * 512];   // coalesced
#pragma unroll
    for (int e = 0; e < 192; ++e) asm volatile("" : "+v"(wv[e]));  // pin: no remat
#pragma unroll
    for (int i = 0; i < 16; ++i)
      *(u32x4*)&whL[(i * 512 + tid) * 4] = *(const u32x4*)&wh16L[(i * 512 + tid) * 4];
  }
  if (tid < 128) h16[tid] = 0u;   // h(0) = 0
  float c_st = 0.f;
  __syncthreads();

  const float* pregs = preg + ((size_t)s * 8 + (d >> 5)) * 128 + (d & 31);

  for (int t = 0; t < TSTEPS; ++t) {
    // pre-gates (owners): issue early, consumed after the dots
    float pg0 = 0.f, pg1 = 0.f, pg2 = 0.f, pg3 = 0.f;
    if (owner) {
      const float* pb = pregs + (size_t)t * 32768;   // + t*32*1024
      pg0 = pb[0]; pg1 = pb[32]; pg2 = pb[64]; pg3 = pb[96];
    }
    // ---- partial dots over this thread's 64 pairs (128 k) ----
    float a0 = 0.f, a1 = 0.f, a2 = 0.f, a3 = 0.f;
    const unsigned* hseg = h16 + kseg * 64;
#pragma unroll
    for (int c = 0; c < 16; ++c) {
      u32x4 h4 = *(const u32x4*)(hseg + c * 4);                  // broadcast read
      u32x4 w3 = *(const u32x4*)&whL[(c * 512 + tid) * 4];       // conflict-free b128
#pragma unroll
      for (int k = 0; k < 4; ++k) {
        a0 = fdot2(wv[0 * 64 + c * 4 + k], h4[k], a0);
        a1 = fdot2(wv[1 * 64 + c * 4 + k], h4[k], a1);
        a2 = fdot2(wv[2 * 64 + c * 4 + k], h4[k], a2);
        a3 = fdot2(w3[k],                  h4[k], a3);
      }
    }
    if (!owner) {   // kseg 1: publish partials
      f32x4 r; r.x = a0; r.y = a1; r.z = a2; r.w = a3;
      *(f32x4*)&accb[d * 4] = r;
    }
    __syncthreads();                 // partials visible; h16 reads done
    if (owner) {
      f32x4 r = *(const f32x4*)&accb[d * 4];
      float gi = a0 + r.x + pg0;
      float gf = a1 + r.y + pg1;
      float gg = a2 + r.z + pg2;
      float go = a3 + r.w + pg3;
      float si = 1.f / (1.f + expf(-gi));
      float sf = 1.f / (1.f + expf(-gf));
      float so = 1.f / (1.f + expf(-go));
      float cc = sf * c_st + si * tanhf(gg);
      float hh = so * tanhf(cc);
      c_st = cc;
      ((_Float16*)h16)[d] = (_Float16)hh;                    // next-step h (fp16)
      hs[(size_t)(t + 1) * 8192 + s * 256 + d] = hh;         // f32 history
    }
    __syncthreads();                 // new h16 + accb reuse protected
  }
}

// ---------------- final: scores, softmax, BCE, argmax ----------------
__global__ void k_final(const float* __restrict__ hs, const int* __restrict__ mask,
                        const float* __restrict__ labels, const float* __restrict__ W2,
                        const float* __restrict__ b2, float* __restrict__ out) {
  __shared__ float scores[32];
  __shared__ float errpart[8];
  int tid = threadIdx.x;
  if (tid < 32) {
    int len = 0;
    for (int t = 0; t < 128; ++t) len += mask[tid * 128 + t];
    if (len < 1) len = 1;
    const float* hl = hs + (size_t)len * 8192 + tid * 256;
    float acc = b2[0];
    for (int k = 0; k < 256; ++k) acc += hl[k] * W2[k];
    scores[tid] = acc;
  }
  __syncthreads();
  if (tid < 8) {
    float sc[4];
#pragma unroll
    for (int i = 0; i < 4; ++i) sc[i] = scores[tid * 4 + i];
    float mx = fmaxf(fmaxf(sc[0], sc[1]), fmaxf(sc[2], sc[3]));
    float ex[4], ssum = 0.f;
#pragma unroll
    for (int i = 0; i < 4; ++i) { ex[i] = expf(sc[i] - mx); ssum += ex[i]; }
    float esum = 0.f; int am = 0; float best = -1e30f;
#pragma unroll
    for (int i = 0; i < 4; ++i) {
      float p = ex[i] / ssum;
      float li = labels[tid * 4 + i];
      esum += fmaxf(p, 0.f) - p * li + log1pf(expf(-fabsf(p)));
      if (p > best) { best = p; am = i; }
    }
    errpart[tid] = esum;
    out[1 + tid] = (float)am;
  }
  __syncthreads();
  if (tid == 0) {
    float e = 0.f;
    for (int i = 0; i < 8; ++i) e += errpart[i];
    out[0] = e / 32.f;
  }
}

extern "C" void kernel_launch(void* const* d_in, const int* in_sizes, int n_in,
                              void* d_out, int out_size, void* d_ws, size_t ws_size,
                              hipStream_t stream) {
  const int*   input_ids  = (const int*)d_in[0];
  const int*   input_mask = (const int*)d_in[1];
  const float* labels     = (const float*)d_in[2];
  const int*   src        = (const int*)d_in[3];
  const int*   dst        = (const int*)d_in[4];
  const float* ev         = (const float*)d_in[5];
  const float* node_emb   = (const float*)d_in[6];
  const float* W1         = (const float*)d_in[7];
  const float* b1         = (const float*)d_in[8];
  const float* w_ih       = (const float*)d_in[9];
  const float* w_hh       = (const float*)d_in[10];
  const float* b_ih       = (const float*)d_in[11];
  const float* b_hh       = (const float*)d_in[12];
  const float* W2         = (const float*)d_in[13];
  const float* b2         = (const float*)d_in[14];
  float* out = (float*)d_out;
  char* ws = (char*)d_ws;
  int*      slotmap = (int*)(ws + OFF_SLOT);
  float*    agg     = (float*)(ws + OFF_AGG);
  float*    cnt     = (float*)(ws + OFF_CNT);
  float*    Wf      = (float*)(ws + OFF_WF);
  float*    biasf   = (float*)(ws + OFF_BIASF);
  float*    preg    = (float*)(ws + OFF_PREG);
  float*    hs      = (float*)(ws + OFF_HS);
  unsigned* wh16A   = (unsigned*)(ws + OFF_WH16A);
  unsigned* wh16L   = (unsigned*)(ws + OFF_WH16L);

  hipLaunchKernelGGL(k_init,    dim3(2048), dim3(256), 0, stream, slotmap, agg, cnt, hs);
  hipLaunchKernelGGL(k_mark,    dim3(16),   dim3(256), 0, stream, input_ids, slotmap);
  hipLaunchKernelGGL(k_edge,    dim3(6250), dim3(256), 0, stream, src, dst, ev, node_emb, slotmap, agg, cnt);
  hipLaunchKernelGGL(k_div,     dim3(2048), dim3(256), 0, stream, agg, cnt);
  hipLaunchKernelGGL(k_fuse,    dim3(1024), dim3(128), 0, stream, w_ih, W1, b1, b_ih, b_hh, Wf, biasf);
  hipLaunchKernelGGL(k_pregemm, dim3(1024), dim3(256), 0, stream, agg, Wf, biasf, slotmap, input_ids, preg);
  hipLaunchKernelGGL(k_wcvt,    dim3(512),  dim3(256), 0, stream, w_hh, wh16A, wh16L);
  hipLaunchKernelGGL(k_lstm,    dim3(NSEQ), dim3(512), 0, stream, wh16A, wh16L, preg, hs);
  hipLaunchKernelGGL(k_final,   dim3(1),    dim3(64),  0, stream, hs, input_mask, labels, W2, b2, out);
}

// Round 10
// 334.878 us; speedup vs baseline: 1.0104x; 1.0104x over previous
//
#include <hip/hip_runtime.h>
#include <math.h>

#define NNODES 100000
#define NEDGES 1600000
#define NPOS   4096      // 32 seqs * 128 steps
#define NSEQ   32
#define TSTEPS 128
#define WRES   92        // register-resident weight words per thread

typedef float f32x4 __attribute__((ext_vector_type(4)));
typedef unsigned u32x4 __attribute__((ext_vector_type(4)));
typedef _Float16 h2v __attribute__((ext_vector_type(2)));

// ---- ws layout (bytes) ----
#define OFF_SLOT   0          // int[100000]  (dead after k_pregemm)
#define OFF_AGG    400128     // float[4096*128] (dead after k_pregemm; overlaid by wh16)
#define OFF_CNT    2497280    // float[4096]
#define OFF_WF     2513664    // float[1024*128]
#define OFF_BIASF  3037952    // float[1024]
#define OFF_PREG   3042048    // float[128][32s][8m][4q][32d]
#define OFF_HS     19819264   // float[129][32][256]
// fp16 weight images overlay the dead agg region (valid only after k_pregemm):
//   wR: u32[92][1024]    (register-resident part)   376832 B
//   wL: u32x4[9][1024]   (LDS-resident part)        147456 B
#define OFF_WH16A  OFF_AGG
#define OFF_WH16L  (OFF_AGG + WRES * 1024 * 4)

// fp16 dot2 with f32 accumulate: D = w.h[0]*h.h[0] + w.h[1]*h.h[1] + acc.
// Products are exact in f32 (11-bit mantissas); only input quantization matters.
static __device__ __forceinline__ float fdot2(unsigned w, unsigned h, float acc) {
#if __has_builtin(__builtin_amdgcn_fdot2)
  h2v wv, hv;
  __builtin_memcpy(&wv, &w, 4);
  __builtin_memcpy(&hv, &h, 4);
  return __builtin_amdgcn_fdot2(wv, hv, acc, false);
#else
  asm("v_dot2_f32_f16 %0, %1, %2, %0" : "+v"(acc) : "v"(w), "v"(h));
  return acc;
#endif
}

// ---------------- init ----------------
__global__ void k_init(int* slotmap, float* agg, float* cnt, float* hs0) {
  int i = blockIdx.x * blockDim.x + threadIdx.x;
  int stride = gridDim.x * blockDim.x;
  for (int idx = i; idx < 4096 * 128; idx += stride) agg[idx] = 0.f;
  for (int idx = i; idx < NNODES; idx += stride) slotmap[idx] = -1;
  for (int idx = i; idx < 4096; idx += stride) cnt[idx] = 0.f;
  for (int idx = i; idx < 8192; idx += stride) hs0[idx] = 0.f;
}

// ---------------- mark needed nodes ----------------
__global__ void k_mark(const int* __restrict__ input_ids, int* __restrict__ slotmap) {
  int p = blockIdx.x * blockDim.x + threadIdx.x;
  if (p < NPOS) atomicCAS(&slotmap[input_ids[p]], -1, p);
}

// ---------------- edge pass: masked segment-sum ----------------
__global__ void k_edge(const int* __restrict__ src, const int* __restrict__ dst,
                       const float* __restrict__ ev, const float* __restrict__ emb,
                       const int* __restrict__ slotmap,
                       float* __restrict__ agg, float* __restrict__ cnt) {
  int e = blockIdx.x * 256 + threadIdx.x;
  int lane = threadIdx.x & 63;
  int d = dst[e];
  int slot = slotmap[d];
  int sn = 0; float vv = 0.f;
  if (slot >= 0) { sn = src[e]; vv = ev[e]; }
  unsigned long long m = __ballot(slot >= 0);
  while (m) {
    int j = __ffsll(m) - 1;
    m &= m - 1;
    int sl = __shfl(slot, j);
    int s2 = __shfl(sn, j);
    float v = __shfl(vv, j);
    float2 em = *(const float2*)&emb[(size_t)s2 * 128 + 2 * lane];
    atomicAdd(&agg[sl * 128 + 2 * lane],     em.x * v);
    atomicAdd(&agg[sl * 128 + 2 * lane + 1], em.y * v);
    if (lane == 0) atomicAdd(&cnt[sl], 1.f);
  }
}

// ---------------- divide by count ----------------
__global__ void k_div(float* __restrict__ agg, const float* __restrict__ cnt) {
  int i = blockIdx.x * blockDim.x + threadIdx.x;
  agg[i] /= fmaxf(cnt[i >> 7], 1.f);
}

// ---------------- fuse W_f = w_ih @ W1, bias_f ----------------
__global__ void k_fuse(const float* __restrict__ w_ih, const float* __restrict__ W1,
                       const float* __restrict__ b1, const float* __restrict__ b_ih,
                       const float* __restrict__ b_hh,
                       float* __restrict__ Wf, float* __restrict__ bf) {
  int row = blockIdx.x;
  int e = threadIdx.x;
  float acc = 0.f;
  for (int m2 = 0; m2 < 256; ++m2) acc += w_ih[row * 256 + m2] * W1[m2 * 128 + e];
  Wf[row * 128 + e] = acc;
  if (e == 0) {
    float bacc = b_ih[row] + b_hh[row];
    for (int m2 = 0; m2 < 256; ++m2) bacc += w_ih[row * 256 + m2] * b1[m2];
    bf[row] = bacc;
  }
}

// ---------------- pre-gates GEMM: preg[t][s][m][q][32d] ----------------
__global__ __launch_bounds__(256, 2) void k_pregemm(
    const float* __restrict__ hnode, const float* __restrict__ Wf,
    const float* __restrict__ bf, const int* __restrict__ slotmap,
    const int* __restrict__ input_ids, float* __restrict__ preg) {
  __shared__ float Ash[64][132];
  __shared__ float Bsh[64][132];
  __shared__ int slots[64];
  int tid = threadIdx.x;
  int bm = (blockIdx.x & 63) * 64;
  int bn = (blockIdx.x >> 6) * 64;
  if (tid < 64) slots[tid] = slotmap[input_ids[bm + tid]];
  __syncthreads();
#pragma unroll
  for (int i = 0; i < 8; ++i) {
    int idx = tid + 256 * i;
    int r = idx >> 5, c = idx & 31;
    *(float4*)&Ash[r][c * 4] = *(const float4*)&hnode[slots[r] * 128 + c * 4];
    *(float4*)&Bsh[r][c * 4] = *(const float4*)&Wf[(bn + r) * 128 + c * 4];
  }
  __syncthreads();
  int tx = tid & 15, ty = tid >> 4;
  float acc[4][4] = {};
  for (int k = 0; k < 128; k += 4) {
    float4 a[4], bb[4];
#pragma unroll
    for (int i = 0; i < 4; ++i) a[i] = *(const float4*)&Ash[tx + 16 * i][k];
#pragma unroll
    for (int j = 0; j < 4; ++j) bb[j] = *(const float4*)&Bsh[ty + 16 * j][k];
#pragma unroll
    for (int i = 0; i < 4; ++i)
#pragma unroll
      for (int j = 0; j < 4; ++j)
        acc[i][j] += a[i].x * bb[j].x + a[i].y * bb[j].y + a[i].z * bb[j].z + a[i].w * bb[j].w;
  }
#pragma unroll
  for (int j = 0; j < 4; ++j) {
    int row = bn + ty + 16 * j;
    float bias = bf[row];
    int q  = row >> 8;
    int mm = (row >> 5) & 7;
    int dl = row & 31;
#pragma unroll
    for (int i = 0; i < 4; ++i) {
      int p = bm + tx + 16 * i;
      int s = p >> 7, tt = p & 127;
      preg[(((size_t)(tt * 32 + s) * 8 + mm) * 4 + q) * 32 + dl] = acc[i][j] + bias;
    }
  }
}

// ---------------- w_hh f32 -> packed fp16 images (RNE) ----------------
// k_lstm thread mapping: tid = kseg*256 + dd (kseg = k>>6), per-thread words:
//   gate q row = q*256+dd, pair p = (k&63)>>1 in 0..31
//   q<2           -> wR word e = q*32 + p          (register-resident)
//   q==2 && p<28  -> wR word e = 64 + p            (register-resident)
//   q==2 && p>=28 -> wL chunk 0, word p-28         (LDS-resident)
//   q==3          -> wL chunk 1+(p>>2), word p&3   (LDS-resident)
__global__ void k_wcvt(const float* __restrict__ w_hh,
                       unsigned* __restrict__ wRo, unsigned* __restrict__ wLo) {
  int idx = blockIdx.x * 256 + threadIdx.x;   // 0..131071
  int row = idx >> 7;          // 0..1023 : q*256 + dd
  int j   = idx & 127;         // global pair index (k = 2j, 2j+1)
  float x0 = w_hh[(size_t)row * 256 + 2 * j];
  float x1 = w_hh[(size_t)row * 256 + 2 * j + 1];
  union { _Float16 f[2]; unsigned u; } pk;
  pk.f[0] = (_Float16)x0;
  pk.f[1] = (_Float16)x1;
  int q = row >> 8, dd = row & 255;
  int kseg = j >> 5, p = j & 31;
  int tid = kseg * 256 + dd;
  if (q < 2) {
    wRo[(q * 32 + p) * 1024 + tid] = pk.u;
  } else if (q == 2 && p < 28) {
    wRo[(64 + p) * 1024 + tid] = pk.u;
  } else if (q == 2) {
    wLo[(0 * 1024 + tid) * 4 + (p - 28)] = pk.u;
  } else {
    wLo[((1 + (p >> 2)) * 1024 + tid) * 4 + (p & 3)] = pk.u;
  }
}

// ---------------- LSTM: ONE sequence per CU, fp16 weights, zero communication ----
// R6-R9: the VGPR budget is hard-pinned at 128/wave on this toolchain (three
// independent attribute mechanisms all produced identical 128-VGPR binaries;
// wv[192] spilled to scratch, re-streamed 768 B/thread/step). Redesign so 128
// IS the right number: 1024 threads (16 waves) x 128 regs = the ENTIRE 512 KB
// RF (at 512 threads half the RF idled). Per thread (kseg=tid>>8 in 0..3,
// d=tid&255): 4 gate rows x 64 k = 128 weight words. 92 register-resident
// (gates 0,1 + 28/32 of gate 2; live set ~123 <= 128 hard cap) + 36 in LDS
// (rest: 147456 B) => all 512 KB of weights on-CU, no streaming, no spill.
// Per step: 128 dot2/thread (~1200 cyc VALU) overlapped with ~147 KB DS reads
// (~1300 cyc) + 4-way partial reduce via LDS + owner gate math.
__global__ __launch_bounds__(1024) void k_lstm(
    const unsigned* __restrict__ wR, const unsigned* __restrict__ wLg,
    const float* __restrict__ preg, float* __restrict__ hs) {
  __shared__ __align__(16) unsigned whL[9 * 1024 * 4];  // 147456 B: LDS weights
  __shared__ __align__(16) unsigned h16[128];           // 256 fp16 h (512 B)
  __shared__ __align__(16) float    accb[3 * 256 * 4];  // 12288 B: kseg1..3 partials
  const int tid  = threadIdx.x;
  const int s    = blockIdx.x;
  const int kseg = tid >> 8;
  const int d    = tid & 255;
  const bool owner = (kseg == 0);

  // ---- prologue: 92 words into VGPRs, 36 words into LDS (both coalesced) ----
  unsigned wv[WRES];
  {
    const unsigned* wa = wR + tid;
#pragma unroll
    for (int e = 0; e < WRES; ++e) wv[e] = wa[e * 1024];
#pragma unroll
    for (int e = 0; e < WRES; ++e) asm volatile("" : "+v"(wv[e]));  // pin: no remat
    const u32x4* srcL = (const u32x4*)wLg;
    u32x4* dstL = (u32x4*)whL;
#pragma unroll
    for (int j = 0; j < 9; ++j) dstL[j * 1024 + tid] = srcL[j * 1024 + tid];
  }
  if (tid < 128) h16[tid] = 0u;   // h(0) = 0
  float c_st = 0.f;
  __syncthreads();

  const float* pregs = preg + ((size_t)s * 8 + (d >> 5)) * 128 + (d & 31);
  const u32x4* Lb   = (const u32x4*)whL + tid;        // chunk j at Lb[j*1024]
  const u32x4* hseg = (const u32x4*)h16 + kseg * 8;   // 8 u32x4 = this kseg's 64 h

  for (int t = 0; t < TSTEPS; ++t) {
    // pre-gates (owners): issue early, consumed after the dots
    float pg0 = 0.f, pg1 = 0.f, pg2 = 0.f, pg3 = 0.f;
    if (owner) {
      const float* pb = pregs + (size_t)t * 32768;   // + t*32*1024
      pg0 = pb[0]; pg1 = pb[32]; pg2 = pb[64]; pg3 = pb[96];
    }
    // ---- partial dots over this thread's 32 pairs (64 k) x 4 gates ----
    float a0 = 0.f, a1 = 0.f, a2 = 0.f, a3 = 0.f;
    u32x4 g2t = Lb[0];                     // gate-2 pairs 28..31
#pragma unroll
    for (int c = 0; c < 8; ++c) {
      u32x4 h4 = hseg[c];                  // broadcast (uniform per wave)
      u32x4 w3 = Lb[(1 + c) * 1024];       // gate-3 pairs 4c..4c+3, conflict-free
#pragma unroll
      for (int k = 0; k < 4; ++k) {
        a0 = fdot2(wv[c * 4 + k],      h4[k], a0);
        a1 = fdot2(wv[32 + c * 4 + k], h4[k], a1);
        a2 = fdot2(c < 7 ? wv[64 + c * 4 + k] : g2t[k], h4[k], a2);
        a3 = fdot2(w3[k],              h4[k], a3);
      }
    }
    if (!owner) {   // ksegs 1..3: publish partials
      f32x4 r; r.x = a0; r.y = a1; r.z = a2; r.w = a3;
      *(f32x4*)&accb[((kseg - 1) * 256 + d) * 4] = r;
    }
    __syncthreads();                 // partials visible; h16 reads done
    if (owner) {
      f32x4 r0 = *(const f32x4*)&accb[(0 * 256 + d) * 4];
      f32x4 r1 = *(const f32x4*)&accb[(1 * 256 + d) * 4];
      f32x4 r2 = *(const f32x4*)&accb[(2 * 256 + d) * 4];
      float gi = a0 + r0.x + r1.x + r2.x + pg0;
      float gf = a1 + r0.y + r1.y + r2.y + pg1;
      float gg = a2 + r0.z + r1.z + r2.z + pg2;
      float go = a3 + r0.w + r1.w + r2.w + pg3;
      float si = 1.f / (1.f + expf(-gi));
      float sf = 1.f / (1.f + expf(-gf));
      float so = 1.f / (1.f + expf(-go));
      float cc = sf * c_st + si * tanhf(gg);
      float hh = so * tanhf(cc);
      c_st = cc;
      ((_Float16*)h16)[d] = (_Float16)hh;                    // next-step h (fp16)
      hs[(size_t)(t + 1) * 8192 + s * 256 + d] = hh;         // f32 history
    }
    __syncthreads();                 // new h16 + accb reuse protected
  }
}

// ---------------- final: scores, softmax, BCE, argmax ----------------
__global__ void k_final(const float* __restrict__ hs, const int* __restrict__ mask,
                        const float* __restrict__ labels, const float* __restrict__ W2,
                        const float* __restrict__ b2, float* __restrict__ out) {
  __shared__ float scores[32];
  __shared__ float errpart[8];
  int tid = threadIdx.x;
  if (tid < 32) {
    int len = 0;
    for (int t = 0; t < 128; ++t) len += mask[tid * 128 + t];
    if (len < 1) len = 1;
    const float* hl = hs + (size_t)len * 8192 + tid * 256;
    float acc = b2[0];
    for (int k = 0; k < 256; ++k) acc += hl[k] * W2[k];
    scores[tid] = acc;
  }
  __syncthreads();
  if (tid < 8) {
    float sc[4];
#pragma unroll
    for (int i = 0; i < 4; ++i) sc[i] = scores[tid * 4 + i];
    float mx = fmaxf(fmaxf(sc[0], sc[1]), fmaxf(sc[2], sc[3]));
    float ex[4], ssum = 0.f;
#pragma unroll
    for (int i = 0; i < 4; ++i) { ex[i] = expf(sc[i] - mx); ssum += ex[i]; }
    float esum = 0.f; int am = 0; float best = -1e30f;
#pragma unroll
    for (int i = 0; i < 4; ++i) {
      float p = ex[i] / ssum;
      float li = labels[tid * 4 + i];
      esum += fmaxf(p, 0.f) - p * li + log1pf(expf(-fabsf(p)));
      if (p > best) { best = p; am = i; }
    }
    errpart[tid] = esum;
    out[1 + tid] = (float)am;
  }
  __syncthreads();
  if (tid == 0) {
    float e = 0.f;
    for (int i = 0; i < 8; ++i) e += errpart[i];
    out[0] = e / 32.f;
  }
}

extern "C" void kernel_launch(void* const* d_in, const int* in_sizes, int n_in,
                              void* d_out, int out_size, void* d_ws, size_t ws_size,
                              hipStream_t stream) {
  const int*   input_ids  = (const int*)d_in[0];
  const int*   input_mask = (const int*)d_in[1];
  const float* labels     = (const float*)d_in[2];
  const int*   src        = (const int*)d_in[3];
  const int*   dst        = (const int*)d_in[4];
  const float* ev         = (const float*)d_in[5];
  const float* node_emb   = (const float*)d_in[6];
  const float* W1         = (const float*)d_in[7];
  const float* b1         = (const float*)d_in[8];
  const float* w_ih       = (const float*)d_in[9];
  const float* w_hh       = (const float*)d_in[10];
  const float* b_ih       = (const float*)d_in[11];
  const float* b_hh       = (const float*)d_in[12];
  const float* W2         = (const float*)d_in[13];
  const float* b2         = (const float*)d_in[14];
  float* out = (float*)d_out;
  char* ws = (char*)d_ws;
  int*      slotmap = (int*)(ws + OFF_SLOT);
  float*    agg     = (float*)(ws + OFF_AGG);
  float*    cnt     = (float*)(ws + OFF_CNT);
  float*    Wf      = (float*)(ws + OFF_WF);
  float*    biasf   = (float*)(ws + OFF_BIASF);
  float*    preg    = (float*)(ws + OFF_PREG);
  float*    hs      = (float*)(ws + OFF_HS);
  unsigned* wh16A   = (unsigned*)(ws + OFF_WH16A);
  unsigned* wh16L   = (unsigned*)(ws + OFF_WH16L);

  hipLaunchKernelGGL(k_init,    dim3(2048), dim3(256),  0, stream, slotmap, agg, cnt, hs);
  hipLaunchKernelGGL(k_mark,    dim3(16),   dim3(256),  0, stream, input_ids, slotmap);
  hipLaunchKernelGGL(k_edge,    dim3(6250), dim3(256),  0, stream, src, dst, ev, node_emb, slotmap, agg, cnt);
  hipLaunchKernelGGL(k_div,     dim3(2048), dim3(256),  0, stream, agg, cnt);
  hipLaunchKernelGGL(k_fuse,    dim3(1024), dim3(128),  0, stream, w_ih, W1, b1, b_ih, b_hh, Wf, biasf);
  hipLaunchKernelGGL(k_pregemm, dim3(1024), dim3(256),  0, stream, agg, Wf, biasf, slotmap, input_ids, preg);
  hipLaunchKernelGGL(k_wcvt,    dim3(512),  dim3(256),  0, stream, w_hh, wh16A, wh16L);
  hipLaunchKernelGGL(k_lstm,    dim3(NSEQ), dim3(1024), 0, stream, wh16A, wh16L, preg, hs);
  hipLaunchKernelGGL(k_final,   dim3(1),    dim3(64),   0, stream, hs, input_mask, labels, W2, b2, out);
}